// Round 14
// baseline (1285.070 us; speedup 1.0000x reference)
//
#include <hip/hip_runtime.h>
#include <math.h>

// ---------------------------------------------------------------------------
// SpatioTemporalOutageModel:
//   GCN(14->64) -> GCN(64->64)+county_bias -> LSTM(64->128, T=336) -> MLP(128->64->1)
//
// R14:
//  - LSTM: h-part weights in LDS (R11 staging) read per-step via 16 BATCHED
//    inline-asm ds_read_b128 (volatile, back-to-back) + single
//    "s_waitcnt lgkmcnt(0)" + sched_barrier(0) (guide rule #18). asm-produced
//    values cannot be rematerialized/split by the allocator -- tests the
//    theory that compiler-generated loads were being serialized with
//    interleaved waits (~1000 VALU-instr/wave/step vs ~200 in source).
//    x-part weights + gbias named/pinned (R6); plain __syncthreads per step.
//  - k_agg2: 8 timesteps per wave (edge metadata amortized 2x, 8 MLP streams).
//  - (R13) fused k_gcn1; folded W2 (no k_tr2); per-node gbias; rcp sig/tanh.
// ---------------------------------------------------------------------------

#define T_DIM 336
#define N_DIM 3233
#define E_DIM 20000
#define FEAT  14
#define D_DIM 64
#define H_DIM 128
#define ET    (E_DIM + N_DIM)     // edges + self loops = 23233

#define LDS_WB   131072                     // h-part weight fragments
#define LDS_XH   (2 * 16 * 136 * 2)         // 8704
#define LDS_TOTAL (LDS_WB + LDS_XH)         // 139776 <= 163840

typedef _Float16 f16;
typedef _Float16 half8_t __attribute__((ext_vector_type(8)));
typedef float float4_t __attribute__((ext_vector_type(4)));

__device__ __forceinline__ float sigf(float x) {
    return __builtin_amdgcn_rcpf(1.f + exp2f(-1.4426950408889634f * x));
}
__device__ __forceinline__ float tanhfast(float x) {
    return 1.f - 2.f * __builtin_amdgcn_rcpf(1.f + exp2f(2.8853900817779268f * x));
}

// ---------------- CSR build (deterministic) ----------------

__global__ void k_init(int* cnt, int* fill) {
    int i = blockIdx.x * 256 + threadIdx.x;
    if (i < N_DIM) { cnt[i] = 0; fill[i] = 0; }
}

__global__ void k_cnt(const int* __restrict__ ei, int* cnt) {
    int e = blockIdx.x * 256 + threadIdx.x;
    if (e < E_DIM) atomicAdd(&cnt[ei[E_DIM + e]], 1);
}

__global__ void k_scan(const int* __restrict__ cnt, int* __restrict__ rowp) {
    __shared__ int csum[1024];
    int tid = threadIdx.x;
    int base = tid * 4;
    int v[4];
    int s = 0;
    #pragma unroll
    for (int m = 0; m < 4; m++) {
        int idx = base + m;
        int len = (idx < N_DIM) ? (cnt[idx] + 1) : 0;
        v[m] = s; s += len;
    }
    csum[tid] = s;
    __syncthreads();
    for (int off = 1; off < 1024; off <<= 1) {
        int t2 = (tid >= off) ? csum[tid - off] : 0;
        __syncthreads();
        csum[tid] += t2;
        __syncthreads();
    }
    int pre = (tid > 0) ? csum[tid - 1] : 0;
    #pragma unroll
    for (int m = 0; m < 4; m++) {
        int idx = base + m;
        if (idx <= N_DIM) rowp[idx] = pre + v[m];
    }
}

__global__ void k_fill(const int* __restrict__ ei, const int* __restrict__ rowp,
                       int* fill, int* __restrict__ eid) {
    int e = blockIdx.x * 256 + threadIdx.x;
    if (e < ET) {
        int d = (e < E_DIM) ? ei[E_DIM + e] : (e - E_DIM);
        int p = rowp[d] + atomicAdd(&fill[d], 1);
        eid[p] = e;
    }
}

__global__ void k_sortdeg(const float* __restrict__ ew, const int* __restrict__ rowp,
                          int* __restrict__ eid, float* __restrict__ dis) {
    int n = blockIdx.x * 256 + threadIdx.x;
    if (n >= N_DIM) return;
    int p0 = rowp[n], p1 = rowp[n + 1];
    for (int i = p0 + 1; i < p1; i++) {
        int key = eid[i];
        int j = i - 1;
        while (j >= p0 && eid[j] > key) { eid[j + 1] = eid[j]; j--; }
        eid[j + 1] = key;
    }
    float deg = 0.f;
    for (int p = p0; p < p1; p++) {
        int e = eid[p];
        deg += (e < E_DIM) ? ew[e] : 1.0f;
    }
    dis[n] = rsqrtf(deg);
}

__global__ void k_csrmat(const int* __restrict__ ei, const float* __restrict__ ew,
                         const float* __restrict__ dis, const int* __restrict__ rowp,
                         const int* __restrict__ eid, int* __restrict__ csrc,
                         float* __restrict__ cnrm) {
    int n = blockIdx.x * 256 + threadIdx.x;
    if (n >= N_DIM) return;
    float dn = dis[n];
    int p0 = rowp[n], p1 = rowp[n + 1];
    for (int p = p0; p < p1; p++) {
        int e = eid[p];
        int s; float w;
        if (e < E_DIM) { s = ei[e]; w = ew[e]; }
        else           { s = e - E_DIM; w = 1.0f; }
        csrc[p] = s;
        cnrm[p] = dis[s] * w * dn;
    }
}

// ---------------- weight prep: fold W2 into Wih, pack B-fragments ----------------
__global__ void k_wprep(const float* __restrict__ W2, const float* __restrict__ Wih,
                        const float* __restrict__ Whh, f16* __restrict__ wfbuf) {
    int idx = blockIdx.x * 256 + threadIdx.x;
    if (idx >= 8 * 4 * 6 * 64) return;
    int lane = idx & 63;
    int ks = (idx >> 6) % 6;
    int ct = ((idx >> 6) / 6) & 3;
    int wv = (idx >> 6) / 24;
    int q = lane >> 4, r = lane & 15;
    int g = 128 * ct + 16 * wv + r;
    f16* dst = wfbuf + (long)idx * 8;
    if (ks < 2) {
        const float* wir = Wih + (long)g * 64;
        #pragma unroll
        for (int j = 0; j < 8; j++) {
            int k = 32 * ks + 8 * q + j;
            const float* w2r = W2 + (long)k * 64;
            float s = 0.f;
            #pragma unroll 16
            for (int d = 0; d < 64; d++) s += w2r[d] * wir[d];
            dst[j] = (f16)s;
        }
    } else {
        const float* src = Whh + (long)g * 128 + 32 * (ks - 2) + 8 * q;
        #pragma unroll
        for (int j = 0; j < 8; j++) dst[j] = (f16)src[j];
    }
}

// gbias[n][g] = bih[g]+bhh[g] + sum_d (b2[d]+county[n][d])*Wih[g][d]
__global__ void k_gbias(const float* __restrict__ county, const float* __restrict__ b2,
                        const float* __restrict__ Wih, const float* __restrict__ bih,
                        const float* __restrict__ bhh, float* __restrict__ gbias) {
    long id = (long)blockIdx.x * 256 + threadIdx.x;
    if (id >= (long)N_DIM * 512) return;
    int n = (int)(id >> 9), g = (int)(id & 511);
    const float* wir = Wih + (long)g * 64;
    const float* cn = county + (long)n * 64;
    float s = bih[g] + bhh[g];
    #pragma unroll 16
    for (int d = 0; d < 64; d++) s += (b2[d] + cn[d]) * wir[d];
    gbias[id] = s;
}

// ---------------- GCN1 fused: h = relu((A.x)@W1 + b1) -> f16 ----------------
__global__ void k_gcn1(const float* __restrict__ x, const int* __restrict__ rowp,
                       const int* __restrict__ csrc, const float* __restrict__ cnrm,
                       const float* __restrict__ W1, const float* __restrict__ b1,
                       f16* __restrict__ h, int tc) {
    __shared__ float g1[4][4][16];   // [wave][tslot][dim]
    int lane = threadIdx.x & 63;
    int wv = threadIdx.x >> 6;
    long wid = ((long)blockIdx.x * 256 + threadIdx.x) >> 6;
    int ntg = (tc + 3) >> 2;
    bool wlive = wid < (long)N_DIM * ntg;

    int n = 0, tg = 0;
    if (wlive) { n = (int)(wid % N_DIM); tg = (int)(wid / N_DIM); }
    int j = lane >> 4, d = lane & 15;
    int tj = 4 * tg + j;
    bool live = wlive && (d < FEAT) && (tj < tc);

    float acc = 0.f;
    if (wlive) {
        int p0 = rowp[n], p1 = rowp[n + 1];
        for (int p = p0; p < p1; p++) {
            int s = csrc[p];
            float w = cnrm[p];
            if (live) acc += w * x[((long)tj * N_DIM + s) * FEAT + d];
        }
    }
    g1[wv][j][d] = acc;
    __syncthreads();

    if (!wlive) return;
    float wc[FEAT];
    #pragma unroll
    for (int k = 0; k < FEAT; k++) wc[k] = W1[k * 64 + lane];
    float bb = b1[lane];
    #pragma unroll
    for (int jj = 0; jj < 4; jj++) {
        int tjj = 4 * tg + jj;
        if (tjj >= tc) break;
        float a = bb;
        #pragma unroll
        for (int k = 0; k < FEAT; k++) a += g1[wv][jj][k] * wc[k];
        h[((long)tjj * N_DIM + n) * 64 + lane] = (f16)fmaxf(a, 0.f);
    }
}

// ---------------- GCN2a: ah = A.h  (f16 gather, 8 timesteps/wave) ----------------
__global__ void k_agg2(const f16* __restrict__ h, const int* __restrict__ rowp,
                       const int* __restrict__ csrc, const float* __restrict__ cnrm,
                       f16* __restrict__ ah, int tc) {
    int lane = threadIdx.x & 63;
    long wid = ((long)blockIdx.x * 256 + threadIdx.x) >> 6;
    int ntg = (tc + 7) >> 3;
    if (wid >= (long)N_DIM * ntg) return;
    int n = (int)(wid % N_DIM);
    int tg = (int)(wid / N_DIM);
    int tb = 8 * tg;
    int nt = min(8, tc - tb);
    float acc[8];
    #pragma unroll
    for (int j = 0; j < 8; j++) acc[j] = 0.f;
    int p0 = rowp[n], p1 = rowp[n + 1];
    for (int p = p0; p < p1; p++) {
        int s = csrc[p];
        float w = cnrm[p];
        const f16* base = h + ((long)tb * N_DIM + s) * 64 + lane;
        #pragma unroll
        for (int j = 0; j < 8; j++)
            if (j < nt) acc[j] += w * (float)base[(long)j * N_DIM * 64];
    }
    f16* dst = ah + ((long)tb * N_DIM + n) * 64 + lane;
    #pragma unroll
    for (int j = 0; j < 8; j++)
        if (j < nt) dst[(long)j * N_DIM * 64] = (f16)acc[j];
}

// ---------------- LSTM chunk: LDS h-weights via BATCHED asm ds_read ----------------
// Wave wv owns gate-types ct={i,f,g,o} x units [16wv,16wv+16). Thread (wv,q,r):
// nodes 4q+reg, unit u=16wv+r -> all 4 gates of (node,u) live in acc{ct}[reg].

#define DECLWX(ct, ks) const half8_t wx_##ct##_##ks = \
    *(const half8_t*)(wfbuf + (long)((((wv * 4 + ct) * 6 + ks) << 6) + lane) * 8)

// batched LDS weight read: asm-produced (cannot be rematerialized/split)
#define DSRW(name, OFFB) half8_t name; \
    asm volatile("ds_read_b128 %0, %1 offset:" #OFFB : "=v"(name) : "v"(wbaddr))

#define MFMA(acc, a_, w_) acc = __builtin_amdgcn_mfma_f32_16x16x32_f16(a_, w_, acc, 0, 0, 0)

#define ELEM(reg) { \
    float gi = acc0[reg], gf = acc1[reg], gg = acc2[reg], go = acc3[reg]; \
    float c = sigf(gf) * cv4[reg] + sigf(gi) * tanhfast(gg); \
    float hh = sigf(go) * tanhfast(c); \
    cv4[reg] = c; hv4[reg] = hh; \
    xh[buf ^ 1][4 * q + reg][u] = (f16)hh; }

__global__ __launch_bounds__(512, 1) void k_lstm(
    const f16* __restrict__ ah, const f16* __restrict__ wfbuf,
    const float* __restrict__ gbias,
    const float* __restrict__ Wm1, const float* __restrict__ bm1,
    const float* __restrict__ Wm2, const float* __restrict__ bm2,
    float* __restrict__ Hst, float* __restrict__ Cst,
    int tc, int do_init, int do_head, float* __restrict__ out) {
    extern __shared__ __align__(16) char smem[];
    f16* wlds = (f16*)smem;                                   // [wv][ct][ks3][lane][8]
    f16 (*xh)[16][136] = (f16(*)[16][136])(smem + LDS_WB);    // h, double-buffered
    float (*hd)[132]   = (float(*)[132])smem;                 // head scratch (aliases wlds)
    float (*zs)[64]    = (float(*)[64])(smem + 8448);         // aliases wlds

    int tid = threadIdx.x;
    int wv = tid >> 6, lane = tid & 63, q = lane >> 4, r = lane & 15;
    int nb = blockIdx.x * 16;
    int cnt = min(16, N_DIM - nb);
    int u = 16 * wv + r;

    // ---- stage h-part weights (ks 2-5) into LDS: 131072 B, coalesced ----
    for (int f = tid; f < 8192; f += 512) {
        int lane2 = f & 63;
        int tt = f >> 6;                // (wv,ct,ks3) flat
        int ks3 = tt & 3, ct2 = (tt >> 2) & 3, wv2 = tt >> 4;
        int src = (((wv2 * 4 + ct2) * 6) + ks3 + 2) * 64 + lane2;
        *(float4_t*)((char*)wlds + (size_t)f * 16) = *(const float4_t*)&wfbuf[(long)src * 8];
    }

    // x-part weights (ks 0-1): named + pinned (R6 config)
    DECLWX(0, 0); DECLWX(0, 1);
    DECLWX(1, 0); DECLWX(1, 1);
    DECLWX(2, 0); DECLWX(2, 1);
    DECLWX(3, 0); DECLWX(3, 1);

    // per-node folded bias: named float4, pinned
    int gn0 = nb + 4 * q;     if (gn0 >= N_DIM) gn0 = N_DIM - 1;
    int gn1 = nb + 4 * q + 1; if (gn1 >= N_DIM) gn1 = N_DIM - 1;
    int gn2 = nb + 4 * q + 2; if (gn2 >= N_DIM) gn2 = N_DIM - 1;
    int gn3 = nb + 4 * q + 3; if (gn3 >= N_DIM) gn3 = N_DIM - 1;
    float4_t gb0, gb1, gb2, gb3;
    gb0[0] = gbias[(long)gn0 * 512 + 0 * 128 + u];
    gb0[1] = gbias[(long)gn1 * 512 + 0 * 128 + u];
    gb0[2] = gbias[(long)gn2 * 512 + 0 * 128 + u];
    gb0[3] = gbias[(long)gn3 * 512 + 0 * 128 + u];
    gb1[0] = gbias[(long)gn0 * 512 + 1 * 128 + u];
    gb1[1] = gbias[(long)gn1 * 512 + 1 * 128 + u];
    gb1[2] = gbias[(long)gn2 * 512 + 1 * 128 + u];
    gb1[3] = gbias[(long)gn3 * 512 + 1 * 128 + u];
    gb2[0] = gbias[(long)gn0 * 512 + 2 * 128 + u];
    gb2[1] = gbias[(long)gn1 * 512 + 2 * 128 + u];
    gb2[2] = gbias[(long)gn2 * 512 + 2 * 128 + u];
    gb2[3] = gbias[(long)gn3 * 512 + 2 * 128 + u];
    gb3[0] = gbias[(long)gn0 * 512 + 3 * 128 + u];
    gb3[1] = gbias[(long)gn1 * 512 + 3 * 128 + u];
    gb3[2] = gbias[(long)gn2 * 512 + 3 * 128 + u];
    gb3[3] = gbias[(long)gn3 * 512 + 3 * 128 + u];
    asm volatile("" : "+v"(gb0), "+v"(gb1), "+v"(gb2), "+v"(gb3));

    // state: named float4 vectors
    float4_t cv4, hv4;
    {
        int node = 4 * q;
        bool lv0 = (!do_init) && (node < cnt);
        bool lv1 = (!do_init) && (node + 1 < cnt);
        bool lv2 = (!do_init) && (node + 2 < cnt);
        bool lv3 = (!do_init) && (node + 3 < cnt);
        hv4[0] = lv0 ? Hst[(long)(nb + node) * H_DIM + u] : 0.f;
        hv4[1] = lv1 ? Hst[(long)(nb + node + 1) * H_DIM + u] : 0.f;
        hv4[2] = lv2 ? Hst[(long)(nb + node + 2) * H_DIM + u] : 0.f;
        hv4[3] = lv3 ? Hst[(long)(nb + node + 3) * H_DIM + u] : 0.f;
        cv4[0] = lv0 ? Cst[(long)(nb + node) * H_DIM + u] : 0.f;
        cv4[1] = lv1 ? Cst[(long)(nb + node + 1) * H_DIM + u] : 0.f;
        cv4[2] = lv2 ? Cst[(long)(nb + node + 2) * H_DIM + u] : 0.f;
        cv4[3] = lv3 ? Cst[(long)(nb + node + 3) * H_DIM + u] : 0.f;
        xh[0][node][u]     = (f16)hv4[0];
        xh[0][node + 1][u] = (f16)hv4[1];
        xh[0][node + 2][u] = (f16)hv4[2];
        xh[0][node + 3][u] = (f16)hv4[3];
    }

    int xrow = nb + r; if (xrow >= N_DIM) xrow = N_DIM - 1;
    half8_t xa = *(const half8_t*)(ah + (long)xrow * 64 + 8 * q);
    half8_t xb = *(const half8_t*)(ah + (long)xrow * 64 + 32 + 8 * q);

    // per-thread LDS byte address of this wave's weight slice (lane*16B)
    unsigned wbaddr = (unsigned)(size_t)wlds + (unsigned)(wv * 16384 + lane * 16);

    int buf = 0;
    __syncthreads();   // weights staged + h[0] visible

    for (int t = 0; t < tc; t++) {
        // ---- batched asm weight reads: 16 x ds_read_b128, back-to-back ----
        DSRW(w_0_2, 0);     DSRW(w_0_3, 1024);  DSRW(w_0_4, 2048);  DSRW(w_0_5, 3072);
        DSRW(w_1_2, 4096);  DSRW(w_1_3, 5120);  DSRW(w_1_4, 6144);  DSRW(w_1_5, 7168);
        DSRW(w_2_2, 8192);  DSRW(w_2_3, 9216);  DSRW(w_2_4, 10240); DSRW(w_2_5, 11264);
        DSRW(w_3_2, 12288); DSRW(w_3_3, 13312); DSRW(w_3_4, 14336); DSRW(w_3_5, 15360);

        half8_t a2 = *(const half8_t*)&xh[buf][r][8 * q];
        half8_t a3 = *(const half8_t*)&xh[buf][r][32 + 8 * q];
        half8_t a4 = *(const half8_t*)&xh[buf][r][64 + 8 * q];
        half8_t a5 = *(const half8_t*)&xh[buf][r][96 + 8 * q];

        float4_t acc0 = gb0, acc1 = gb1, acc2 = gb2, acc3 = gb3;

        // x-part first (no LDS dependence)
        MFMA(acc0, xa, wx_0_0); MFMA(acc1, xa, wx_1_0); MFMA(acc2, xa, wx_2_0); MFMA(acc3, xa, wx_3_0);
        MFMA(acc0, xb, wx_0_1); MFMA(acc1, xb, wx_1_1); MFMA(acc2, xb, wx_2_1); MFMA(acc3, xb, wx_3_1);

        // prefetch next x
        int tn = (t + 1 < tc) ? t + 1 : t;
        const f16* xp = ah + ((long)tn * N_DIM + xrow) * 64;
        xa = *(const half8_t*)(xp + 8 * q);
        xb = *(const half8_t*)(xp + 32 + 8 * q);

        // one wait for the whole weight batch + hard fence (rule #18)
        asm volatile("s_waitcnt lgkmcnt(0)" ::: "memory");
        __builtin_amdgcn_sched_barrier(0);

        MFMA(acc0, a2, w_0_2); MFMA(acc1, a2, w_1_2); MFMA(acc2, a2, w_2_2); MFMA(acc3, a2, w_3_2);
        MFMA(acc0, a3, w_0_3); MFMA(acc1, a3, w_1_3); MFMA(acc2, a3, w_2_3); MFMA(acc3, a3, w_3_3);
        MFMA(acc0, a4, w_0_4); MFMA(acc1, a4, w_1_4); MFMA(acc2, a4, w_2_4); MFMA(acc3, a4, w_3_4);
        MFMA(acc0, a5, w_0_5); MFMA(acc1, a5, w_1_5); MFMA(acc2, a5, w_2_5); MFMA(acc3, a5, w_3_5);

        ELEM(0) ELEM(1) ELEM(2) ELEM(3)

        __syncthreads();
        buf ^= 1;
    }

    {
        int node = 4 * q;
        if (node < cnt)     { Hst[(long)(nb + node) * H_DIM + u] = hv4[0];
                              Cst[(long)(nb + node) * H_DIM + u] = cv4[0]; }
        if (node + 1 < cnt) { Hst[(long)(nb + node + 1) * H_DIM + u] = hv4[1];
                              Cst[(long)(nb + node + 1) * H_DIM + u] = cv4[1]; }
        if (node + 2 < cnt) { Hst[(long)(nb + node + 2) * H_DIM + u] = hv4[2];
                              Cst[(long)(nb + node + 2) * H_DIM + u] = cv4[2]; }
        if (node + 3 < cnt) { Hst[(long)(nb + node + 3) * H_DIM + u] = hv4[3];
                              Cst[(long)(nb + node + 3) * H_DIM + u] = cv4[3]; }
    }
    if (!do_head) return;

    // weights in LDS are dead past the loop's final barrier -> reuse as scratch
    hd[4 * q + 0][u] = hv4[0];
    hd[4 * q + 1][u] = hv4[1];
    hd[4 * q + 2][u] = hv4[2];
    hd[4 * q + 3][u] = hv4[3];
    __syncthreads();

    for (int i = tid; i < 16 * 64; i += 512) {
        int n = i >> 6, m = i & 63;
        float a = bm1[m];
        #pragma unroll 8
        for (int k = 0; k < H_DIM; k++) a += hd[n][k] * Wm1[k * 64 + m];
        zs[n][m] = fmaxf(a, 0.f);
    }
    __syncthreads();
    if (tid < cnt) {
        float a = bm2[0];
        #pragma unroll 8
        for (int m = 0; m < 64; m++) a += zs[tid][m] * Wm2[m];
        out[nb + tid] = a;
    }
}

// ---------------------------------------------------------------------------

extern "C" void kernel_launch(void* const* d_in, const int* in_sizes, int n_in,
                              void* d_out, int out_size, void* d_ws, size_t ws_size,
                              hipStream_t stream) {
    const float* x   = (const float*)d_in[0];
    const int*   ei  = (const int*)d_in[1];
    const float* ew  = (const float*)d_in[2];
    const float* W1  = (const float*)d_in[3];
    const float* b1  = (const float*)d_in[4];
    const float* W2  = (const float*)d_in[5];
    const float* b2  = (const float*)d_in[6];
    const float* cb  = (const float*)d_in[7];
    const float* Wih = (const float*)d_in[8];
    const float* Whh = (const float*)d_in[9];
    const float* bih = (const float*)d_in[10];
    const float* bhh = (const float*)d_in[11];
    const float* Wm1 = (const float*)d_in[12];
    const float* bm1 = (const float*)d_in[13];
    const float* Wm2 = (const float*)d_in[14];
    const float* bm2 = (const float*)d_in[15];
    float* out = (float*)d_out;
    (void)in_sizes; (void)n_in; (void)out_size;

    // allow >64KB dynamic LDS for k_lstm (host-side, capture-safe)
    hipFuncSetAttribute((const void*)k_lstm,
                        hipFuncAttributeMaxDynamicSharedMemorySize, LDS_TOTAL);

    char* ws = (char*)d_ws;
    size_t off = 0;
    auto alloc = [&](size_t bytes) -> char* {
        char* p = ws + off;
        off = (off + bytes + 255) & ~(size_t)255;
        return p;
    };
    float* dis   = (float*)alloc(N_DIM * 4);
    int*   cnt   = (int*)alloc(N_DIM * 4);
    int*   fill  = (int*)alloc(N_DIM * 4);
    int*   rowp  = (int*)alloc((N_DIM + 1) * 4);
    int*   eid   = (int*)alloc(ET * 4);
    int*   csrc  = (int*)alloc(ET * 4);
    float* cnrm  = (float*)alloc(ET * 4);
    float* Hst   = (float*)alloc((size_t)N_DIM * H_DIM * 4);
    float* Cst   = (float*)alloc((size_t)N_DIM * H_DIM * 4);
    f16*   wfbuf = (f16*)alloc((size_t)8 * 4 * 6 * 64 * 8 * 2);
    float* gbias = (float*)alloc((size_t)N_DIM * 512 * 4);

    // largest Tc dividing 336 whose chunk buffers (rows*256B: h + ah f16) fit
    const int cand[] = {336, 168, 112, 84, 56, 48, 28, 16, 8, 4};
    int Tc = 4;
    for (int i = 0; i < 10; i++) {
        size_t need = off + (size_t)cand[i] * N_DIM * 256 + 4096;
        if (need <= ws_size) { Tc = cand[i]; break; }
    }
    long rows = (long)Tc * N_DIM;
    f16* hbuf  = (f16*)alloc(rows * 128);   // h f16
    f16* ahbuf = (f16*)alloc(rows * 128);   // ah f16

    // --- one-time: CSR build + weight fold/pack + per-node gate bias ---
    k_init<<<(N_DIM + 255) / 256, 256, 0, stream>>>(cnt, fill);
    k_cnt<<<(E_DIM + 255) / 256, 256, 0, stream>>>(ei, cnt);
    k_scan<<<1, 1024, 0, stream>>>(cnt, rowp);
    k_fill<<<(ET + 255) / 256, 256, 0, stream>>>(ei, rowp, fill, eid);
    k_sortdeg<<<(N_DIM + 255) / 256, 256, 0, stream>>>(ew, rowp, eid, dis);
    k_csrmat<<<(N_DIM + 255) / 256, 256, 0, stream>>>(ei, ew, dis, rowp, eid, csrc, cnrm);
    k_wprep<<<48, 256, 0, stream>>>(W2, Wih, Whh, wfbuf);
    k_gbias<<<(int)(((long)N_DIM * 512 + 255) / 256), 256, 0, stream>>>(cb, b2, Wih, bih, bhh, gbias);

    int ntg4 = (Tc + 3) >> 2;
    int ntg8 = (Tc + 7) >> 3;
    int g1Blocks = (int)(((long)N_DIM * ntg4 + 3) / 4);
    int a2Blocks = (int)(((long)N_DIM * ntg8 + 3) / 4);
    int lblocks  = (N_DIM + 15) / 16;
    int nChunks  = T_DIM / Tc;

    for (int c = 0; c < nChunks; c++) {
        long t0 = (long)c * Tc;
        k_gcn1<<<g1Blocks, 256, 0, stream>>>(x + t0 * N_DIM * FEAT, rowp, csrc, cnrm,
                                             W1, b1, hbuf, Tc);
        k_agg2<<<a2Blocks, 256, 0, stream>>>(hbuf, rowp, csrc, cnrm, ahbuf, Tc);
        k_lstm<<<lblocks, 512, LDS_TOTAL, stream>>>(ahbuf, wfbuf, gbias, Wm1, bm1, Wm2, bm2,
                                                    Hst, Cst, Tc, c == 0 ? 1 : 0,
                                                    c == nChunks - 1 ? 1 : 0, out);
    }
}

// Round 15
// 1242.470 us; speedup vs baseline: 1.0343x; 1.0343x over previous
//
#include <hip/hip_runtime.h>
#include <math.h>

// ---------------------------------------------------------------------------
// SpatioTemporalOutageModel:
//   GCN(14->64) -> GCN(64->64)+county_bias -> LSTM(64->128, T=336) -> MLP(128->64->1)
//
// R15 (consolidation):
//  - k_lstm: byte-exact R13/R6 revert (measured optimum 222us/84 steps).
//    R6-R14 established: step cost invariant to weight-delivery mechanism
//    (L2/AGPR/LDS/named/ping-pong/asm-batched); allocator caps ~92 VGPR.
//  - k_agg2: 8 timesteps/wave (R14, measured -52us on the GCN stage).
//  - Decoupled chunking: LSTM chunk Tc and GCN sub-chunk Th selected at
//    runtime from ws_size (known ws in [100,152) MB). Tc=168 halves LSTM
//    dispatch count; hbuf sized by Th keeps workspace in budget.
// ---------------------------------------------------------------------------

#define T_DIM 336
#define N_DIM 3233
#define E_DIM 20000
#define FEAT  14
#define D_DIM 64
#define H_DIM 128
#define ET    (E_DIM + N_DIM)     // edges + self loops = 23233

typedef _Float16 f16;
typedef _Float16 half8_t __attribute__((ext_vector_type(8)));
typedef float float4_t __attribute__((ext_vector_type(4)));

__device__ __forceinline__ float sigf(float x) {
    return __builtin_amdgcn_rcpf(1.f + exp2f(-1.4426950408889634f * x));
}
__device__ __forceinline__ float tanhfast(float x) {
    return 1.f - 2.f * __builtin_amdgcn_rcpf(1.f + exp2f(2.8853900817779268f * x));
}

// ---------------- CSR build (deterministic) ----------------

__global__ void k_init(int* cnt, int* fill) {
    int i = blockIdx.x * 256 + threadIdx.x;
    if (i < N_DIM) { cnt[i] = 0; fill[i] = 0; }
}

__global__ void k_cnt(const int* __restrict__ ei, int* cnt) {
    int e = blockIdx.x * 256 + threadIdx.x;
    if (e < E_DIM) atomicAdd(&cnt[ei[E_DIM + e]], 1);
}

__global__ void k_scan(const int* __restrict__ cnt, int* __restrict__ rowp) {
    __shared__ int csum[1024];
    int tid = threadIdx.x;
    int base = tid * 4;
    int v[4];
    int s = 0;
    #pragma unroll
    for (int m = 0; m < 4; m++) {
        int idx = base + m;
        int len = (idx < N_DIM) ? (cnt[idx] + 1) : 0;
        v[m] = s; s += len;
    }
    csum[tid] = s;
    __syncthreads();
    for (int off = 1; off < 1024; off <<= 1) {
        int t2 = (tid >= off) ? csum[tid - off] : 0;
        __syncthreads();
        csum[tid] += t2;
        __syncthreads();
    }
    int pre = (tid > 0) ? csum[tid - 1] : 0;
    #pragma unroll
    for (int m = 0; m < 4; m++) {
        int idx = base + m;
        if (idx <= N_DIM) rowp[idx] = pre + v[m];
    }
}

__global__ void k_fill(const int* __restrict__ ei, const int* __restrict__ rowp,
                       int* fill, int* __restrict__ eid) {
    int e = blockIdx.x * 256 + threadIdx.x;
    if (e < ET) {
        int d = (e < E_DIM) ? ei[E_DIM + e] : (e - E_DIM);
        int p = rowp[d] + atomicAdd(&fill[d], 1);
        eid[p] = e;
    }
}

__global__ void k_sortdeg(const float* __restrict__ ew, const int* __restrict__ rowp,
                          int* __restrict__ eid, float* __restrict__ dis) {
    int n = blockIdx.x * 256 + threadIdx.x;
    if (n >= N_DIM) return;
    int p0 = rowp[n], p1 = rowp[n + 1];
    for (int i = p0 + 1; i < p1; i++) {
        int key = eid[i];
        int j = i - 1;
        while (j >= p0 && eid[j] > key) { eid[j + 1] = eid[j]; j--; }
        eid[j + 1] = key;
    }
    float deg = 0.f;
    for (int p = p0; p < p1; p++) {
        int e = eid[p];
        deg += (e < E_DIM) ? ew[e] : 1.0f;
    }
    dis[n] = rsqrtf(deg);
}

__global__ void k_csrmat(const int* __restrict__ ei, const float* __restrict__ ew,
                         const float* __restrict__ dis, const int* __restrict__ rowp,
                         const int* __restrict__ eid, int* __restrict__ csrc,
                         float* __restrict__ cnrm) {
    int n = blockIdx.x * 256 + threadIdx.x;
    if (n >= N_DIM) return;
    float dn = dis[n];
    int p0 = rowp[n], p1 = rowp[n + 1];
    for (int p = p0; p < p1; p++) {
        int e = eid[p];
        int s; float w;
        if (e < E_DIM) { s = ei[e]; w = ew[e]; }
        else           { s = e - E_DIM; w = 1.0f; }
        csrc[p] = s;
        cnrm[p] = dis[s] * w * dn;
    }
}

// ---------------- weight prep: fold W2 into Wih, pack B-fragments ----------------
__global__ void k_wprep(const float* __restrict__ W2, const float* __restrict__ Wih,
                        const float* __restrict__ Whh, f16* __restrict__ wfbuf) {
    int idx = blockIdx.x * 256 + threadIdx.x;
    if (idx >= 8 * 4 * 6 * 64) return;
    int lane = idx & 63;
    int ks = (idx >> 6) % 6;
    int ct = ((idx >> 6) / 6) & 3;
    int wv = (idx >> 6) / 24;
    int q = lane >> 4, r = lane & 15;
    int g = 128 * ct + 16 * wv + r;
    f16* dst = wfbuf + (long)idx * 8;
    if (ks < 2) {
        const float* wir = Wih + (long)g * 64;
        #pragma unroll
        for (int j = 0; j < 8; j++) {
            int k = 32 * ks + 8 * q + j;
            const float* w2r = W2 + (long)k * 64;
            float s = 0.f;
            #pragma unroll 16
            for (int d = 0; d < 64; d++) s += w2r[d] * wir[d];
            dst[j] = (f16)s;
        }
    } else {
        const float* src = Whh + (long)g * 128 + 32 * (ks - 2) + 8 * q;
        #pragma unroll
        for (int j = 0; j < 8; j++) dst[j] = (f16)src[j];
    }
}

// gbias[n][g] = bih[g]+bhh[g] + sum_d (b2[d]+county[n][d])*Wih[g][d]
__global__ void k_gbias(const float* __restrict__ county, const float* __restrict__ b2,
                        const float* __restrict__ Wih, const float* __restrict__ bih,
                        const float* __restrict__ bhh, float* __restrict__ gbias) {
    long id = (long)blockIdx.x * 256 + threadIdx.x;
    if (id >= (long)N_DIM * 512) return;
    int n = (int)(id >> 9), g = (int)(id & 511);
    const float* wir = Wih + (long)g * 64;
    const float* cn = county + (long)n * 64;
    float s = bih[g] + bhh[g];
    #pragma unroll 16
    for (int d = 0; d < 64; d++) s += (b2[d] + cn[d]) * wir[d];
    gbias[id] = s;
}

// ---------------- GCN1 fused: h = relu((A.x)@W1 + b1) -> f16 (Th steps) ----------------
__global__ void k_gcn1(const float* __restrict__ x, const int* __restrict__ rowp,
                       const int* __restrict__ csrc, const float* __restrict__ cnrm,
                       const float* __restrict__ W1, const float* __restrict__ b1,
                       f16* __restrict__ h, int tc) {
    __shared__ float g1[4][4][16];   // [wave][tslot][dim]
    int lane = threadIdx.x & 63;
    int wv = threadIdx.x >> 6;
    long wid = ((long)blockIdx.x * 256 + threadIdx.x) >> 6;
    int ntg = (tc + 3) >> 2;
    bool wlive = wid < (long)N_DIM * ntg;

    int n = 0, tg = 0;
    if (wlive) { n = (int)(wid % N_DIM); tg = (int)(wid / N_DIM); }
    int j = lane >> 4, d = lane & 15;
    int tj = 4 * tg + j;
    bool live = wlive && (d < FEAT) && (tj < tc);

    float acc = 0.f;
    if (wlive) {
        int p0 = rowp[n], p1 = rowp[n + 1];
        for (int p = p0; p < p1; p++) {
            int s = csrc[p];
            float w = cnrm[p];
            if (live) acc += w * x[((long)tj * N_DIM + s) * FEAT + d];
        }
    }
    g1[wv][j][d] = acc;
    __syncthreads();

    if (!wlive) return;
    float wc[FEAT];
    #pragma unroll
    for (int k = 0; k < FEAT; k++) wc[k] = W1[k * 64 + lane];
    float bb = b1[lane];
    #pragma unroll
    for (int jj = 0; jj < 4; jj++) {
        int tjj = 4 * tg + jj;
        if (tjj >= tc) break;
        float a = bb;
        #pragma unroll
        for (int k = 0; k < FEAT; k++) a += g1[wv][jj][k] * wc[k];
        h[((long)tjj * N_DIM + n) * 64 + lane] = (f16)fmaxf(a, 0.f);
    }
}

// ---------------- GCN2a: ah = A.h  (f16 gather, 8 timesteps/wave) ----------------
__global__ void k_agg2(const f16* __restrict__ h, const int* __restrict__ rowp,
                       const int* __restrict__ csrc, const float* __restrict__ cnrm,
                       f16* __restrict__ ah, int tc) {
    int lane = threadIdx.x & 63;
    long wid = ((long)blockIdx.x * 256 + threadIdx.x) >> 6;
    int ntg = (tc + 7) >> 3;
    if (wid >= (long)N_DIM * ntg) return;
    int n = (int)(wid % N_DIM);
    int tg = (int)(wid / N_DIM);
    int tb = 8 * tg;
    int nt = min(8, tc - tb);
    float acc[8];
    #pragma unroll
    for (int j = 0; j < 8; j++) acc[j] = 0.f;
    int p0 = rowp[n], p1 = rowp[n + 1];
    for (int p = p0; p < p1; p++) {
        int s = csrc[p];
        float w = cnrm[p];
        const f16* base = h + ((long)tb * N_DIM + s) * 64 + lane;
        #pragma unroll
        for (int j = 0; j < 8; j++)
            if (j < nt) acc[j] += w * (float)base[(long)j * N_DIM * 64];
    }
    f16* dst = ah + ((long)tb * N_DIM + n) * 64 + lane;
    #pragma unroll
    for (int j = 0; j < 8; j++)
        if (j < nt) dst[(long)j * N_DIM * 64] = (f16)acc[j];
}

// ---------------- LSTM chunk (exact R6/R13: f16 MFMA, pinned frags) + MLP head -----
// Wave wv owns gate-types ct={i,f,g,o} x units [16wv,16wv+16). Thread (wv,q,r):
// nodes 4q+reg, unit u=16wv+r -> all 4 gates of (node,u) live in acc[ct][reg].
__global__ __attribute__((amdgpu_flat_work_group_size(512, 512), amdgpu_waves_per_eu(2, 2)))
void k_lstm(
    const f16* __restrict__ ah, const f16* __restrict__ wfbuf,
    const float* __restrict__ gbias,
    const float* __restrict__ Wm1, const float* __restrict__ bm1,
    const float* __restrict__ Wm2, const float* __restrict__ bm2,
    float* __restrict__ Hst, float* __restrict__ Cst,
    int tc, int do_init, int do_head, float* __restrict__ out) {
    __shared__ __align__(16) f16   xh[2][16][136];   // h, double-buffered
    __shared__ __align__(16) float hd[16][132];      // head scratch
    __shared__ __align__(16) float zs[16][64];

    int tid = threadIdx.x;
    int wv = tid >> 6, lane = tid & 63, q = lane >> 4, r = lane & 15;
    int nb = blockIdx.x * 16;
    int cnt = min(16, N_DIM - nb);
    int u = 16 * wv + r;

    // weight fragments, pinned as asm outputs (R6 configuration)
    float4_t wfr[4][6];
    #pragma unroll
    for (int ct = 0; ct < 4; ct++)
        #pragma unroll
        for (int ks = 0; ks < 6; ks++)
            wfr[ct][ks] = *(const float4_t*)&wfbuf[(long)((((wv * 4 + ct) * 6 + ks) << 6) + lane) * 8];
    #pragma unroll
    for (int ct = 0; ct < 4; ct++)
        #pragma unroll
        for (int ks = 0; ks < 6; ks++)
            asm volatile("" : "+v"(wfr[ct][ks]));

    // per-node folded bias -- pinned
    float gb[4][4];
    #pragma unroll
    for (int reg = 0; reg < 4; reg++) {
        int node = 4 * q + reg;
        int gn = nb + node; if (gn >= N_DIM) gn = N_DIM - 1;
        #pragma unroll
        for (int ct = 0; ct < 4; ct++)
            gb[ct][reg] = gbias[(long)gn * 512 + 128 * ct + u];
    }
    #pragma unroll
    for (int ct = 0; ct < 4; ct++)
        #pragma unroll
        for (int reg = 0; reg < 4; reg++)
            asm volatile("" : "+v"(gb[ct][reg]));

    // state in VGPRs
    float cv[4], hvv[4];
    #pragma unroll
    for (int reg = 0; reg < 4; reg++) {
        int node = 4 * q + reg;
        bool live = (!do_init) && (node < cnt);
        hvv[reg] = live ? Hst[(long)(nb + node) * H_DIM + u] : 0.f;
        cv[reg]  = live ? Cst[(long)(nb + node) * H_DIM + u] : 0.f;
        xh[0][node][u] = (f16)hvv[reg];
    }

    int xrow = nb + r; if (xrow >= N_DIM) xrow = N_DIM - 1;
    half8_t xa = *(const half8_t*)(ah + (long)xrow * 64 + 8 * q);
    half8_t xb = *(const half8_t*)(ah + (long)xrow * 64 + 32 + 8 * q);

    int buf = 0;
    __syncthreads();

    for (int t = 0; t < tc; t++) {
        half8_t a2 = *(const half8_t*)&xh[buf][r][8 * q];
        half8_t a3 = *(const half8_t*)&xh[buf][r][32 + 8 * q];
        half8_t a4 = *(const half8_t*)&xh[buf][r][64 + 8 * q];
        half8_t a5 = *(const half8_t*)&xh[buf][r][96 + 8 * q];

        float4_t acc[4];
        #pragma unroll
        for (int ct = 0; ct < 4; ct++) {
            acc[ct][0] = gb[ct][0]; acc[ct][1] = gb[ct][1];
            acc[ct][2] = gb[ct][2]; acc[ct][3] = gb[ct][3];
        }
        #pragma unroll
        for (int ct = 0; ct < 4; ct++)
            acc[ct] = __builtin_amdgcn_mfma_f32_16x16x32_f16(xa, __builtin_bit_cast(half8_t, wfr[ct][0]), acc[ct], 0, 0, 0);
        #pragma unroll
        for (int ct = 0; ct < 4; ct++)
            acc[ct] = __builtin_amdgcn_mfma_f32_16x16x32_f16(xb, __builtin_bit_cast(half8_t, wfr[ct][1]), acc[ct], 0, 0, 0);

        // prefetch next x now -- xa/xb dead; latency hidden under groups 2-5
        int tn = (t + 1 < tc) ? t + 1 : t;
        const f16* xp = ah + ((long)tn * N_DIM + xrow) * 64;
        xa = *(const half8_t*)(xp + 8 * q);
        xb = *(const half8_t*)(xp + 32 + 8 * q);

        #pragma unroll
        for (int ct = 0; ct < 4; ct++)
            acc[ct] = __builtin_amdgcn_mfma_f32_16x16x32_f16(a2, __builtin_bit_cast(half8_t, wfr[ct][2]), acc[ct], 0, 0, 0);
        #pragma unroll
        for (int ct = 0; ct < 4; ct++)
            acc[ct] = __builtin_amdgcn_mfma_f32_16x16x32_f16(a3, __builtin_bit_cast(half8_t, wfr[ct][3]), acc[ct], 0, 0, 0);
        #pragma unroll
        for (int ct = 0; ct < 4; ct++)
            acc[ct] = __builtin_amdgcn_mfma_f32_16x16x32_f16(a4, __builtin_bit_cast(half8_t, wfr[ct][4]), acc[ct], 0, 0, 0);
        #pragma unroll
        for (int ct = 0; ct < 4; ct++)
            acc[ct] = __builtin_amdgcn_mfma_f32_16x16x32_f16(a5, __builtin_bit_cast(half8_t, wfr[ct][5]), acc[ct], 0, 0, 0);

        // elementwise in-register
        #pragma unroll
        for (int reg = 0; reg < 4; reg++) {
            float gi = acc[0][reg], gf = acc[1][reg], gg = acc[2][reg], go = acc[3][reg];
            float c = sigf(gf) * cv[reg] + sigf(gi) * tanhfast(gg);
            float hh = sigf(go) * tanhfast(c);
            cv[reg] = c; hvv[reg] = hh;
            xh[buf ^ 1][4 * q + reg][u] = (f16)hh;
        }
        __syncthreads();
        buf ^= 1;
    }

    #pragma unroll
    for (int reg = 0; reg < 4; reg++) {
        int node = 4 * q + reg;
        if (node < cnt) {
            Hst[(long)(nb + node) * H_DIM + u] = hvv[reg];
            Cst[(long)(nb + node) * H_DIM + u] = cv[reg];
        }
    }
    if (!do_head) return;

    #pragma unroll
    for (int reg = 0; reg < 4; reg++) hd[4 * q + reg][u] = hvv[reg];
    __syncthreads();

    for (int i = tid; i < 16 * 64; i += 512) {
        int n = i >> 6, m = i & 63;
        float a = bm1[m];
        #pragma unroll 8
        for (int k = 0; k < H_DIM; k++) a += hd[n][k] * Wm1[k * 64 + m];
        zs[n][m] = fmaxf(a, 0.f);
    }
    __syncthreads();
    if (tid < cnt) {
        float a = bm2[0];
        #pragma unroll 8
        for (int m = 0; m < 64; m++) a += zs[tid][m] * Wm2[m];
        out[nb + tid] = a;
    }
}

// ---------------------------------------------------------------------------

extern "C" void kernel_launch(void* const* d_in, const int* in_sizes, int n_in,
                              void* d_out, int out_size, void* d_ws, size_t ws_size,
                              hipStream_t stream) {
    const float* x   = (const float*)d_in[0];
    const int*   ei  = (const int*)d_in[1];
    const float* ew  = (const float*)d_in[2];
    const float* W1  = (const float*)d_in[3];
    const float* b1  = (const float*)d_in[4];
    const float* W2  = (const float*)d_in[5];
    const float* b2  = (const float*)d_in[6];
    const float* cb  = (const float*)d_in[7];
    const float* Wih = (const float*)d_in[8];
    const float* Whh = (const float*)d_in[9];
    const float* bih = (const float*)d_in[10];
    const float* bhh = (const float*)d_in[11];
    const float* Wm1 = (const float*)d_in[12];
    const float* bm1 = (const float*)d_in[13];
    const float* Wm2 = (const float*)d_in[14];
    const float* bm2 = (const float*)d_in[15];
    float* out = (float*)d_out;
    (void)in_sizes; (void)n_in; (void)out_size;

    char* ws = (char*)d_ws;
    size_t off = 0;
    auto alloc = [&](size_t bytes) -> char* {
        char* p = ws + off;
        off = (off + bytes + 255) & ~(size_t)255;
        return p;
    };
    float* dis   = (float*)alloc(N_DIM * 4);
    int*   cnt   = (int*)alloc(N_DIM * 4);
    int*   fill  = (int*)alloc(N_DIM * 4);
    int*   rowp  = (int*)alloc((N_DIM + 1) * 4);
    int*   eid   = (int*)alloc(ET * 4);
    int*   csrc  = (int*)alloc(ET * 4);
    float* cnrm  = (float*)alloc(ET * 4);
    float* Hst   = (float*)alloc((size_t)N_DIM * H_DIM * 4);
    float* Cst   = (float*)alloc((size_t)N_DIM * H_DIM * 4);
    f16*   wfbuf = (f16*)alloc((size_t)8 * 4 * 6 * 64 * 8 * 2);
    float* gbias = (float*)alloc((size_t)N_DIM * 512 * 4);

    // decoupled chunk selection: (Tc = LSTM chunk, Th = GCN sub-chunk)
    // workspace need: ahbuf (Tc rows x 128B) + hbuf (Th rows x 128B)
    const int optTc[] = {168, 168, 168, 84, 84, 56, 28, 8, 4};
    const int optTh[] = { 84,  56,  28, 84, 42, 56, 28, 8, 4};
    int Tc = 4, Th = 4;
    for (int i = 0; i < 9; i++) {
        size_t need = off + (size_t)optTc[i] * N_DIM * 128
                          + (size_t)optTh[i] * N_DIM * 128 + 4096;
        if (need <= ws_size) { Tc = optTc[i]; Th = optTh[i]; break; }
    }
    f16* ahbuf = (f16*)alloc((size_t)Tc * N_DIM * 128);   // ah f16, Tc steps
    f16* hbuf  = (f16*)alloc((size_t)Th * N_DIM * 128);   // h f16, Th steps

    // --- one-time: CSR build + weight fold/pack + per-node gate bias ---
    k_init<<<(N_DIM + 255) / 256, 256, 0, stream>>>(cnt, fill);
    k_cnt<<<(E_DIM + 255) / 256, 256, 0, stream>>>(ei, cnt);
    k_scan<<<1, 1024, 0, stream>>>(cnt, rowp);
    k_fill<<<(ET + 255) / 256, 256, 0, stream>>>(ei, rowp, fill, eid);
    k_sortdeg<<<(N_DIM + 255) / 256, 256, 0, stream>>>(ew, rowp, eid, dis);
    k_csrmat<<<(N_DIM + 255) / 256, 256, 0, stream>>>(ei, ew, dis, rowp, eid, csrc, cnrm);
    k_wprep<<<48, 256, 0, stream>>>(W2, Wih, Whh, wfbuf);
    k_gbias<<<(int)(((long)N_DIM * 512 + 255) / 256), 256, 0, stream>>>(cb, b2, Wih, bih, bhh, gbias);

    int ntg4 = (Th + 3) >> 2;
    int ntg8 = (Th + 7) >> 3;
    int g1Blocks = (int)(((long)N_DIM * ntg4 + 3) / 4);
    int a2Blocks = (int)(((long)N_DIM * ntg8 + 3) / 4);
    int lblocks  = (N_DIM + 15) / 16;
    int nChunks  = T_DIM / Tc;
    int nSub     = Tc / Th;

    for (int c = 0; c < nChunks; c++) {
        for (int s = 0; s < nSub; s++) {
            long t0 = (long)c * Tc + (long)s * Th;
            k_gcn1<<<g1Blocks, 256, 0, stream>>>(x + t0 * N_DIM * FEAT, rowp, csrc, cnrm,
                                                 W1, b1, hbuf, Th);
            k_agg2<<<a2Blocks, 256, 0, stream>>>(hbuf, rowp, csrc, cnrm,
                                                 ahbuf + (long)s * Th * N_DIM * 64, Th);
        }
        k_lstm<<<lblocks, 512, 0, stream>>>(ahbuf, wfbuf, gbias, Wm1, bm1, Wm2, bm2,
                                            Hst, Cst, Tc, c == 0 ? 1 : 0,
                                            c == nChunks - 1 ? 1 : 0, out);
    }
}

// Round 16
// 1078.589 us; speedup vs baseline: 1.1914x; 1.1519x over previous
//
#include <hip/hip_runtime.h>
#include <math.h>

// ---------------------------------------------------------------------------
// SpatioTemporalOutageModel:
//   GCN(14->64) -> GCN(64->64)+county_bias -> LSTM(64->128, T=336) -> MLP(128->64->1)
//
// R16 = byte-exact R13 (best measured: 1161us) + ONE isolated change:
//  - k_agg2 vectorized to f16x2 (4B/lane): lane=(t-half, dim-pair), same
//    4 timesteps/wave + wave count, HALF the VMEM instructions per edge.
//    (R15 established agg2-8t was a regression -- reverted; R14's apparent
//    win was confounded by its slower LSTM.)
//  - LSTM: R6/R13 config (measured optimum 222us/84 steps; step cost proven
//    invariant to all 9 weight-delivery/barrier schemes tried in R6-R14).
// ---------------------------------------------------------------------------

#define T_DIM 336
#define N_DIM 3233
#define E_DIM 20000
#define FEAT  14
#define D_DIM 64
#define H_DIM 128
#define ET    (E_DIM + N_DIM)     // edges + self loops = 23233

typedef _Float16 f16;
typedef _Float16 half8_t __attribute__((ext_vector_type(8)));
typedef _Float16 half2_t __attribute__((ext_vector_type(2)));
typedef float float4_t __attribute__((ext_vector_type(4)));

__device__ __forceinline__ float sigf(float x) {
    return __builtin_amdgcn_rcpf(1.f + exp2f(-1.4426950408889634f * x));
}
__device__ __forceinline__ float tanhfast(float x) {
    return 1.f - 2.f * __builtin_amdgcn_rcpf(1.f + exp2f(2.8853900817779268f * x));
}

// ---------------- CSR build (deterministic) ----------------

__global__ void k_init(int* cnt, int* fill) {
    int i = blockIdx.x * 256 + threadIdx.x;
    if (i < N_DIM) { cnt[i] = 0; fill[i] = 0; }
}

__global__ void k_cnt(const int* __restrict__ ei, int* cnt) {
    int e = blockIdx.x * 256 + threadIdx.x;
    if (e < E_DIM) atomicAdd(&cnt[ei[E_DIM + e]], 1);
}

__global__ void k_scan(const int* __restrict__ cnt, int* __restrict__ rowp) {
    __shared__ int csum[1024];
    int tid = threadIdx.x;
    int base = tid * 4;
    int v[4];
    int s = 0;
    #pragma unroll
    for (int m = 0; m < 4; m++) {
        int idx = base + m;
        int len = (idx < N_DIM) ? (cnt[idx] + 1) : 0;
        v[m] = s; s += len;
    }
    csum[tid] = s;
    __syncthreads();
    for (int off = 1; off < 1024; off <<= 1) {
        int t2 = (tid >= off) ? csum[tid - off] : 0;
        __syncthreads();
        csum[tid] += t2;
        __syncthreads();
    }
    int pre = (tid > 0) ? csum[tid - 1] : 0;
    #pragma unroll
    for (int m = 0; m < 4; m++) {
        int idx = base + m;
        if (idx <= N_DIM) rowp[idx] = pre + v[m];
    }
}

__global__ void k_fill(const int* __restrict__ ei, const int* __restrict__ rowp,
                       int* fill, int* __restrict__ eid) {
    int e = blockIdx.x * 256 + threadIdx.x;
    if (e < ET) {
        int d = (e < E_DIM) ? ei[E_DIM + e] : (e - E_DIM);
        int p = rowp[d] + atomicAdd(&fill[d], 1);
        eid[p] = e;
    }
}

__global__ void k_sortdeg(const float* __restrict__ ew, const int* __restrict__ rowp,
                          int* __restrict__ eid, float* __restrict__ dis) {
    int n = blockIdx.x * 256 + threadIdx.x;
    if (n >= N_DIM) return;
    int p0 = rowp[n], p1 = rowp[n + 1];
    for (int i = p0 + 1; i < p1; i++) {
        int key = eid[i];
        int j = i - 1;
        while (j >= p0 && eid[j] > key) { eid[j + 1] = eid[j]; j--; }
        eid[j + 1] = key;
    }
    float deg = 0.f;
    for (int p = p0; p < p1; p++) {
        int e = eid[p];
        deg += (e < E_DIM) ? ew[e] : 1.0f;
    }
    dis[n] = rsqrtf(deg);
}

__global__ void k_csrmat(const int* __restrict__ ei, const float* __restrict__ ew,
                         const float* __restrict__ dis, const int* __restrict__ rowp,
                         const int* __restrict__ eid, int* __restrict__ csrc,
                         float* __restrict__ cnrm) {
    int n = blockIdx.x * 256 + threadIdx.x;
    if (n >= N_DIM) return;
    float dn = dis[n];
    int p0 = rowp[n], p1 = rowp[n + 1];
    for (int p = p0; p < p1; p++) {
        int e = eid[p];
        int s; float w;
        if (e < E_DIM) { s = ei[e]; w = ew[e]; }
        else           { s = e - E_DIM; w = 1.0f; }
        csrc[p] = s;
        cnrm[p] = dis[s] * w * dn;
    }
}

// ---------------- weight prep: fold W2 into Wih, pack B-fragments ----------------
__global__ void k_wprep(const float* __restrict__ W2, const float* __restrict__ Wih,
                        const float* __restrict__ Whh, f16* __restrict__ wfbuf) {
    int idx = blockIdx.x * 256 + threadIdx.x;
    if (idx >= 8 * 4 * 6 * 64) return;
    int lane = idx & 63;
    int ks = (idx >> 6) % 6;
    int ct = ((idx >> 6) / 6) & 3;
    int wv = (idx >> 6) / 24;
    int q = lane >> 4, r = lane & 15;
    int g = 128 * ct + 16 * wv + r;
    f16* dst = wfbuf + (long)idx * 8;
    if (ks < 2) {
        const float* wir = Wih + (long)g * 64;
        #pragma unroll
        for (int j = 0; j < 8; j++) {
            int k = 32 * ks + 8 * q + j;
            const float* w2r = W2 + (long)k * 64;
            float s = 0.f;
            #pragma unroll 16
            for (int d = 0; d < 64; d++) s += w2r[d] * wir[d];
            dst[j] = (f16)s;
        }
    } else {
        const float* src = Whh + (long)g * 128 + 32 * (ks - 2) + 8 * q;
        #pragma unroll
        for (int j = 0; j < 8; j++) dst[j] = (f16)src[j];
    }
}

// gbias[n][g] = bih[g]+bhh[g] + sum_d (b2[d]+county[n][d])*Wih[g][d]
__global__ void k_gbias(const float* __restrict__ county, const float* __restrict__ b2,
                        const float* __restrict__ Wih, const float* __restrict__ bih,
                        const float* __restrict__ bhh, float* __restrict__ gbias) {
    long id = (long)blockIdx.x * 256 + threadIdx.x;
    if (id >= (long)N_DIM * 512) return;
    int n = (int)(id >> 9), g = (int)(id & 511);
    const float* wir = Wih + (long)g * 64;
    const float* cn = county + (long)n * 64;
    float s = bih[g] + bhh[g];
    #pragma unroll 16
    for (int d = 0; d < 64; d++) s += (b2[d] + cn[d]) * wir[d];
    gbias[id] = s;
}

// ---------------- GCN1 fused: h = relu((A.x)@W1 + b1) -> f16 ----------------
__global__ void k_gcn1(const float* __restrict__ x, const int* __restrict__ rowp,
                       const int* __restrict__ csrc, const float* __restrict__ cnrm,
                       const float* __restrict__ W1, const float* __restrict__ b1,
                       f16* __restrict__ h, int tc) {
    __shared__ float g1[4][4][16];   // [wave][tslot][dim]
    int lane = threadIdx.x & 63;
    int wv = threadIdx.x >> 6;
    long wid = ((long)blockIdx.x * 256 + threadIdx.x) >> 6;
    int ntg = (tc + 3) >> 2;
    bool wlive = wid < (long)N_DIM * ntg;

    int n = 0, tg = 0;
    if (wlive) { n = (int)(wid % N_DIM); tg = (int)(wid / N_DIM); }
    int j = lane >> 4, d = lane & 15;
    int tj = 4 * tg + j;
    bool live = wlive && (d < FEAT) && (tj < tc);

    float acc = 0.f;
    if (wlive) {
        int p0 = rowp[n], p1 = rowp[n + 1];
        for (int p = p0; p < p1; p++) {
            int s = csrc[p];
            float w = cnrm[p];
            if (live) acc += w * x[((long)tj * N_DIM + s) * FEAT + d];
        }
    }
    g1[wv][j][d] = acc;
    __syncthreads();

    if (!wlive) return;
    float wc[FEAT];
    #pragma unroll
    for (int k = 0; k < FEAT; k++) wc[k] = W1[k * 64 + lane];
    float bb = b1[lane];
    #pragma unroll
    for (int jj = 0; jj < 4; jj++) {
        int tjj = 4 * tg + jj;
        if (tjj >= tc) break;
        float a = bb;
        #pragma unroll
        for (int k = 0; k < FEAT; k++) a += g1[wv][jj][k] * wc[k];
        h[((long)tjj * N_DIM + n) * 64 + lane] = (f16)fmaxf(a, 0.f);
    }
}

// ---------------- GCN2a: ah = A.h  (f16x2 gather, 4 timesteps/wave) ----------------
// lane = (half, dim-pair): half=lane>>5 selects t in {tb+half, tb+2+half};
// d2=lane&31 covers dims [2*d2, 2*d2+1]. 2 x 4B loads/edge (was 4 x 2B).
__global__ void k_agg2(const f16* __restrict__ h, const int* __restrict__ rowp,
                       const int* __restrict__ csrc, const float* __restrict__ cnrm,
                       f16* __restrict__ ah, int tc) {
    int lane = threadIdx.x & 63;
    long wid = ((long)blockIdx.x * 256 + threadIdx.x) >> 6;
    int ntg = (tc + 3) >> 2;
    if (wid >= (long)N_DIM * ntg) return;
    int n = (int)(wid % N_DIM);
    int tg = (int)(wid / N_DIM);
    int tb = 4 * tg;
    int half = lane >> 5, d2 = (lane & 31) << 1;
    int ta = tb + half;        // first t this lane covers
    int tbp = tb + 2 + half;   // second t
    bool la = ta < tc, lb = tbp < tc;
    float a0 = 0.f, a1 = 0.f, b0 = 0.f, b1v = 0.f;
    int p0 = rowp[n], p1 = rowp[n + 1];
    const long strideT2 = (long)2 * N_DIM * 64;
    for (int p = p0; p < p1; p++) {
        int s = csrc[p];
        float w = cnrm[p];
        const f16* base = h + ((long)ta * N_DIM + s) * 64 + d2;
        if (la) {
            half2_t va = *(const half2_t*)base;
            a0 += w * (float)va[0];
            a1 += w * (float)va[1];
        }
        if (lb) {
            half2_t vb = *(const half2_t*)(base + strideT2);
            b0  += w * (float)vb[0];
            b1v += w * (float)vb[1];
        }
    }
    f16* dst = ah + ((long)ta * N_DIM + n) * 64 + d2;
    if (la) { half2_t oa; oa[0] = (f16)a0; oa[1] = (f16)a1; *(half2_t*)dst = oa; }
    if (lb) { half2_t ob; ob[0] = (f16)b0; ob[1] = (f16)b1v; *(half2_t*)(dst + strideT2) = ob; }
}

// ---------------- LSTM chunk (exact R6/R13: f16 MFMA, pinned frags) + MLP head -----
// Wave wv owns gate-types ct={i,f,g,o} x units [16wv,16wv+16). Thread (wv,q,r):
// nodes 4q+reg, unit u=16wv+r -> all 4 gates of (node,u) live in acc[ct][reg].
__global__ __attribute__((amdgpu_flat_work_group_size(512, 512), amdgpu_waves_per_eu(2, 2)))
void k_lstm(
    const f16* __restrict__ ah, const f16* __restrict__ wfbuf,
    const float* __restrict__ gbias,
    const float* __restrict__ Wm1, const float* __restrict__ bm1,
    const float* __restrict__ Wm2, const float* __restrict__ bm2,
    float* __restrict__ Hst, float* __restrict__ Cst,
    int tc, int do_init, int do_head, float* __restrict__ out) {
    __shared__ __align__(16) f16   xh[2][16][136];   // h, double-buffered
    __shared__ __align__(16) float hd[16][132];      // head scratch
    __shared__ __align__(16) float zs[16][64];

    int tid = threadIdx.x;
    int wv = tid >> 6, lane = tid & 63, q = lane >> 4, r = lane & 15;
    int nb = blockIdx.x * 16;
    int cnt = min(16, N_DIM - nb);
    int u = 16 * wv + r;

    // weight fragments, pinned as asm outputs (R6 configuration)
    float4_t wfr[4][6];
    #pragma unroll
    for (int ct = 0; ct < 4; ct++)
        #pragma unroll
        for (int ks = 0; ks < 6; ks++)
            wfr[ct][ks] = *(const float4_t*)&wfbuf[(long)((((wv * 4 + ct) * 6 + ks) << 6) + lane) * 8];
    #pragma unroll
    for (int ct = 0; ct < 4; ct++)
        #pragma unroll
        for (int ks = 0; ks < 6; ks++)
            asm volatile("" : "+v"(wfr[ct][ks]));

    // per-node folded bias -- pinned
    float gb[4][4];
    #pragma unroll
    for (int reg = 0; reg < 4; reg++) {
        int node = 4 * q + reg;
        int gn = nb + node; if (gn >= N_DIM) gn = N_DIM - 1;
        #pragma unroll
        for (int ct = 0; ct < 4; ct++)
            gb[ct][reg] = gbias[(long)gn * 512 + 128 * ct + u];
    }
    #pragma unroll
    for (int ct = 0; ct < 4; ct++)
        #pragma unroll
        for (int reg = 0; reg < 4; reg++)
            asm volatile("" : "+v"(gb[ct][reg]));

    // state in VGPRs
    float cv[4], hvv[4];
    #pragma unroll
    for (int reg = 0; reg < 4; reg++) {
        int node = 4 * q + reg;
        bool live = (!do_init) && (node < cnt);
        hvv[reg] = live ? Hst[(long)(nb + node) * H_DIM + u] : 0.f;
        cv[reg]  = live ? Cst[(long)(nb + node) * H_DIM + u] : 0.f;
        xh[0][node][u] = (f16)hvv[reg];
    }

    int xrow = nb + r; if (xrow >= N_DIM) xrow = N_DIM - 1;
    half8_t xa = *(const half8_t*)(ah + (long)xrow * 64 + 8 * q);
    half8_t xb = *(const half8_t*)(ah + (long)xrow * 64 + 32 + 8 * q);

    int buf = 0;
    __syncthreads();

    for (int t = 0; t < tc; t++) {
        half8_t a2 = *(const half8_t*)&xh[buf][r][8 * q];
        half8_t a3 = *(const half8_t*)&xh[buf][r][32 + 8 * q];
        half8_t a4 = *(const half8_t*)&xh[buf][r][64 + 8 * q];
        half8_t a5 = *(const half8_t*)&xh[buf][r][96 + 8 * q];

        float4_t acc[4];
        #pragma unroll
        for (int ct = 0; ct < 4; ct++) {
            acc[ct][0] = gb[ct][0]; acc[ct][1] = gb[ct][1];
            acc[ct][2] = gb[ct][2]; acc[ct][3] = gb[ct][3];
        }
        #pragma unroll
        for (int ct = 0; ct < 4; ct++)
            acc[ct] = __builtin_amdgcn_mfma_f32_16x16x32_f16(xa, __builtin_bit_cast(half8_t, wfr[ct][0]), acc[ct], 0, 0, 0);
        #pragma unroll
        for (int ct = 0; ct < 4; ct++)
            acc[ct] = __builtin_amdgcn_mfma_f32_16x16x32_f16(xb, __builtin_bit_cast(half8_t, wfr[ct][1]), acc[ct], 0, 0, 0);

        // prefetch next x now -- xa/xb dead; latency hidden under groups 2-5
        int tn = (t + 1 < tc) ? t + 1 : t;
        const f16* xp = ah + ((long)tn * N_DIM + xrow) * 64;
        xa = *(const half8_t*)(xp + 8 * q);
        xb = *(const half8_t*)(xp + 32 + 8 * q);

        #pragma unroll
        for (int ct = 0; ct < 4; ct++)
            acc[ct] = __builtin_amdgcn_mfma_f32_16x16x32_f16(a2, __builtin_bit_cast(half8_t, wfr[ct][2]), acc[ct], 0, 0, 0);
        #pragma unroll
        for (int ct = 0; ct < 4; ct++)
            acc[ct] = __builtin_amdgcn_mfma_f32_16x16x32_f16(a3, __builtin_bit_cast(half8_t, wfr[ct][3]), acc[ct], 0, 0, 0);
        #pragma unroll
        for (int ct = 0; ct < 4; ct++)
            acc[ct] = __builtin_amdgcn_mfma_f32_16x16x32_f16(a4, __builtin_bit_cast(half8_t, wfr[ct][4]), acc[ct], 0, 0, 0);
        #pragma unroll
        for (int ct = 0; ct < 4; ct++)
            acc[ct] = __builtin_amdgcn_mfma_f32_16x16x32_f16(a5, __builtin_bit_cast(half8_t, wfr[ct][5]), acc[ct], 0, 0, 0);

        // elementwise in-register
        #pragma unroll
        for (int reg = 0; reg < 4; reg++) {
            float gi = acc[0][reg], gf = acc[1][reg], gg = acc[2][reg], go = acc[3][reg];
            float c = sigf(gf) * cv[reg] + sigf(gi) * tanhfast(gg);
            float hh = sigf(go) * tanhfast(c);
            cv[reg] = c; hvv[reg] = hh;
            xh[buf ^ 1][4 * q + reg][u] = (f16)hh;
        }
        __syncthreads();
        buf ^= 1;
    }

    #pragma unroll
    for (int reg = 0; reg < 4; reg++) {
        int node = 4 * q + reg;
        if (node < cnt) {
            Hst[(long)(nb + node) * H_DIM + u] = hvv[reg];
            Cst[(long)(nb + node) * H_DIM + u] = cv[reg];
        }
    }
    if (!do_head) return;

    #pragma unroll
    for (int reg = 0; reg < 4; reg++) hd[4 * q + reg][u] = hvv[reg];
    __syncthreads();

    for (int i = tid; i < 16 * 64; i += 512) {
        int n = i >> 6, m = i & 63;
        float a = bm1[m];
        #pragma unroll 8
        for (int k = 0; k < H_DIM; k++) a += hd[n][k] * Wm1[k * 64 + m];
        zs[n][m] = fmaxf(a, 0.f);
    }
    __syncthreads();
    if (tid < cnt) {
        float a = bm2[0];
        #pragma unroll 8
        for (int m = 0; m < 64; m++) a += zs[tid][m] * Wm2[m];
        out[nb + tid] = a;
    }
}

// ---------------------------------------------------------------------------

extern "C" void kernel_launch(void* const* d_in, const int* in_sizes, int n_in,
                              void* d_out, int out_size, void* d_ws, size_t ws_size,
                              hipStream_t stream) {
    const float* x   = (const float*)d_in[0];
    const int*   ei  = (const int*)d_in[1];
    const float* ew  = (const float*)d_in[2];
    const float* W1  = (const float*)d_in[3];
    const float* b1  = (const float*)d_in[4];
    const float* W2  = (const float*)d_in[5];
    const float* b2  = (const float*)d_in[6];
    const float* cb  = (const float*)d_in[7];
    const float* Wih = (const float*)d_in[8];
    const float* Whh = (const float*)d_in[9];
    const float* bih = (const float*)d_in[10];
    const float* bhh = (const float*)d_in[11];
    const float* Wm1 = (const float*)d_in[12];
    const float* bm1 = (const float*)d_in[13];
    const float* Wm2 = (const float*)d_in[14];
    const float* bm2 = (const float*)d_in[15];
    float* out = (float*)d_out;
    (void)in_sizes; (void)n_in; (void)out_size;

    char* ws = (char*)d_ws;
    size_t off = 0;
    auto alloc = [&](size_t bytes) -> char* {
        char* p = ws + off;
        off = (off + bytes + 255) & ~(size_t)255;
        return p;
    };
    float* dis   = (float*)alloc(N_DIM * 4);
    int*   cnt   = (int*)alloc(N_DIM * 4);
    int*   fill  = (int*)alloc(N_DIM * 4);
    int*   rowp  = (int*)alloc((N_DIM + 1) * 4);
    int*   eid   = (int*)alloc(ET * 4);
    int*   csrc  = (int*)alloc(ET * 4);
    float* cnrm  = (float*)alloc(ET * 4);
    float* Hst   = (float*)alloc((size_t)N_DIM * H_DIM * 4);
    float* Cst   = (float*)alloc((size_t)N_DIM * H_DIM * 4);
    f16*   wfbuf = (f16*)alloc((size_t)8 * 4 * 6 * 64 * 8 * 2);
    float* gbias = (float*)alloc((size_t)N_DIM * 512 * 4);

    // largest Tc dividing 336 whose chunk buffers (rows*256B: h + ah f16) fit
    const int cand[] = {336, 168, 112, 84, 56, 48, 28, 16, 8, 4};
    int Tc = 4;
    for (int i = 0; i < 10; i++) {
        size_t need = off + (size_t)cand[i] * N_DIM * 256 + 4096;
        if (need <= ws_size) { Tc = cand[i]; break; }
    }
    long rows = (long)Tc * N_DIM;
    f16* hbuf  = (f16*)alloc(rows * 128);   // h f16
    f16* ahbuf = (f16*)alloc(rows * 128);   // ah f16

    // --- one-time: CSR build + weight fold/pack + per-node gate bias ---
    k_init<<<(N_DIM + 255) / 256, 256, 0, stream>>>(cnt, fill);
    k_cnt<<<(E_DIM + 255) / 256, 256, 0, stream>>>(ei, cnt);
    k_scan<<<1, 1024, 0, stream>>>(cnt, rowp);
    k_fill<<<(ET + 255) / 256, 256, 0, stream>>>(ei, rowp, fill, eid);
    k_sortdeg<<<(N_DIM + 255) / 256, 256, 0, stream>>>(ew, rowp, eid, dis);
    k_csrmat<<<(N_DIM + 255) / 256, 256, 0, stream>>>(ei, ew, dis, rowp, eid, csrc, cnrm);
    k_wprep<<<48, 256, 0, stream>>>(W2, Wih, Whh, wfbuf);
    k_gbias<<<(int)(((long)N_DIM * 512 + 255) / 256), 256, 0, stream>>>(cb, b2, Wih, bih, bhh, gbias);

    int ntg = (Tc + 3) >> 2;
    long aggWaves = (long)N_DIM * ntg;
    int aggBlocks = (int)((aggWaves + 3) / 4);
    int lblocks   = (N_DIM + 15) / 16;
    int nChunks   = T_DIM / Tc;

    for (int c = 0; c < nChunks; c++) {
        long t0 = (long)c * Tc;
        k_gcn1<<<aggBlocks, 256, 0, stream>>>(x + t0 * N_DIM * FEAT, rowp, csrc, cnrm,
                                              W1, b1, hbuf, Tc);
        k_agg2<<<aggBlocks, 256, 0, stream>>>(hbuf, rowp, csrc, cnrm, ahbuf, Tc);
        k_lstm<<<lblocks, 512, 0, stream>>>(ahbuf, wfbuf, gbias, Wm1, bm1, Wm2, bm2,
                                            Hst, Cst, Tc, c == 0 ? 1 : 0,
                                            c == nChunks - 1 ? 1 : 0, out);
    }
}